// Round 14
// baseline (1214.643 us; speedup 1.0000x reference)
//
#include <hip/hip_runtime.h>
#include <math.h>

// LotkaVolterra neural-SDE rollout. P=4096, H=256, 100 sequential steps.
// R29 = R24 structure at PB=8 / 512 blocks -> TWO CO-RESIDENT BLOCKS PER CU.
// Rationale: R27's "4 waves/SIMD infeasible" claim was WRONG -- VGPR_Count is
// 128, so 4 waves/SIMD (= 2 blocks x 8 waves per CU) fits the 512-reg budget
// exactly. Occupancy was capped by LDS (99.8KB -> 1 block/CU) and grid (256
// blocks). At 40% LDS-pipe / 21% VALU / 22% MFMA utilization, the ~60% idle
// (barrier drains + wave-0 tail + LDS latency) is exactly what a second
// resident block overlaps. PB=8 halves per-block LDS to ~54KB (2x54=108<=160).
// __launch_bounds__(512,4) pins the allocator at 128 regs (spill canary:
// FETCH/WRITE + VGPR_Count). MFMA geometry UNCHANGED: A-reads use row=col&7
// (lanes 8-15 broadcast-duplicate rows 0-7 -- same-address reads are free,
// m136); only quads 0-1 store D-rows<8. Layer-0: path=wv, 4 cols/lane
// (fewer live regs than R24). Per-block distinct LDS traffic halves -> two
// blocks ~= today's per-CU LDS load with 2x TLP.
// Decisive counters: OccupancyPercent ~45% (vs 23), steady ~150-175us.
// If VGPR>128 or occupancy stays 23%: revert to R24 and declare roofline.

#define PP 4096
#define HH 256
#define LT 100
#define PB 8
#define SH 264          // bf16 LDS row stride: 528 B = 33*16B (MUST stay 16B-multiple)
#define NT 512

typedef __attribute__((ext_vector_type(8))) short short8;
typedef __attribute__((ext_vector_type(4))) short short4v;
typedef __attribute__((ext_vector_type(4))) float float4v;

__device__ __forceinline__ float softplus_fast(float x) {
    const float e = __expf(-fabsf(x));
    return fmaxf(x, 0.0f) + __logf(1.0f + e);
}
__device__ __forceinline__ unsigned short f2bf(float f) {   // RNE fp32->bf16
    unsigned int u = __float_as_uint(f);
    u += 0x7fffu + ((u >> 16) & 1u);
    return (unsigned short)(u >> 16);
}
// one-instruction packed RNE conversion: D = {lo16: bf16(a), hi16: bf16(b)}
__device__ __forceinline__ unsigned int cvtpk(float a, float b) {
    unsigned int r;
    asm("v_cvt_pk_bf16_f32 %0, %1, %2" : "=v"(r) : "v"(a), "v"(b));
    return r;
}
__device__ __forceinline__ float4 ldg4(const float* p) { return *(const float4*)p; }

// ---- parallel prologue: block b handles t = b+1 (R14-verified correct) ----
__global__ void prep_cfeat(const float* __restrict__ W0, const float* __restrict__ b0,
                           const float* __restrict__ feature_init,
                           const float* __restrict__ tn_store,
                           const float* __restrict__ x1_store,
                           const float* __restrict__ x2_store,
                           float* __restrict__ cfeat) {
    const int t = blockIdx.x + 1;             // 1..99
    const int col = threadIdx.x;
    // exact sequential fp32 tval chain (matches ref's scan accumulation)
    float tval = feature_init[0];
    for (int i = 0; i < t; ++i) tval += 0.1f;
    const float tn = tn_store[t - 1], x1 = x1_store[t - 1], x2 = x2_store[t - 1];
    const float w2c = W0[2 * 256 + col], w3c = W0[3 * 256 + col];
    const float w46 = W0[4 * 256 + col] + W0[6 * 256 + col];
    const float w57 = W0[5 * 256 + col] + W0[7 * 256 + col];
    cfeat[t * 256 + col] = b0[col] + tval * w2c + tn * w3c + x1 * w46 + x2 * w57;
}

// 256->256 bf16 MFMA layer, TWO ADJACENT col-groups/wave (paired-col mapping),
// PB=8: A-row = col&7 (lanes 8-15 broadcast rows 0-7); only quads 0-1 store.
__device__ __forceinline__ void mfma256_reg2(const short8 (&wf)[2][8], float bv0, float bv1,
                                             const unsigned short* __restrict__ hin,
                                             unsigned short* __restrict__ hout,
                                             int wv, int lane) {
    const int quad = lane >> 4, col = lane & 15;
    float4v acc0 = {bv0, bv0, bv0, bv0};
    float4v acc1 = {bv1, bv1, bv1, bv1};
    const unsigned short* arow = hin + (col & 7) * SH + quad * 8;
#pragma unroll
    for (int ks = 0; ks < 8; ++ks) {
        short8 a = *(const short8*)(arow + ks * 32);
        acc0 = __builtin_amdgcn_mfma_f32_16x16x32_bf16(a, wf[0][ks], acc0, 0, 0, 0);
        acc1 = __builtin_amdgcn_mfma_f32_16x16x32_bf16(a, wf[1][ks], acc1, 0, 0, 0);
    }
    // C/D layout: col = lane&15, row p = quad*4 + reg (m89-verified).
    // Valid paths p<8 -> quads 0,1 only store.
    if (quad < 2) {
#pragma unroll
        for (int r = 0; r < 4; ++r) {
            const unsigned int pk = cvtpk(fmaxf(acc0[r], 0.0f), fmaxf(acc1[r], 0.0f));
            *(unsigned int*)&hout[(quad * 4 + r) * SH + wv * 32 + 2 * col] = pk;
        }
    }
}

__global__ __launch_bounds__(NT, 4)
void lv_kernel(const float* __restrict__ W0, const float* __restrict__ b0,
               const float* __restrict__ W1, const float* __restrict__ b1,
               const float* __restrict__ W2, const float* __restrict__ b2,
               const float* __restrict__ W3, const float* __restrict__ b3,
               const float* __restrict__ obs_init, const float* __restrict__ feature_init,
               const float* __restrict__ path_seed,
               const float* __restrict__ cfeat,
               float* __restrict__ out) {
    __shared__ unsigned short hA[PB * SH];
    __shared__ unsigned short hB[PB * SH];
    __shared__ unsigned short hC[PB * SH];
    __shared__ __align__(16) unsigned short w3l[4096];   // W3 fragments (zero-padded)
    __shared__ __align__(16) float w0l[512];             // W0 rows 0,1
    __shared__ __align__(16) float sseed[LT * 16];       // ALL seeds for this block (6.4KB)
    __shared__ float st[PB][2];                          // path state
    __shared__ __align__(16) float pbuf[PB * 202];
    __shared__ __align__(16) float mbuf[PB * 200];
    __shared__ __align__(16) float sbuf[PB * 400];

    const int tid = threadIdx.x;
    const int lane = tid & 63;
    const int wv = tid >> 6;            // wave 0..7; owns col pairs wv*32+2c,+1
    const int quad = lane >> 4;
    const int col = lane & 15;
    const int lp = wv;                  // layer-0 path handled by this wave
    const int pbase = blockIdx.x * PB;

    const float DTf = 0.1f;
    const float SQ = 0.31622776601683794f;  // sqrt(0.1)

    // ---- per-wave W1/W2 B-fragments (2 ADJACENT col-groups) from global ----
    short8 wf1[2][8], wf2[2][8];
    {
#pragma unroll
        for (int g = 0; g < 2; ++g) {
            const int colc = wv * 32 + 2 * col + g;
#pragma unroll
            for (int ks = 0; ks < 8; ++ks) {
#pragma unroll
                for (int j = 0; j < 8; ++j) {
                    const int k = ks * 32 + quad * 8 + j;
                    wf1[g][ks][j] = (short)f2bf(W1[k * 256 + colc]);
                    wf2[g][ks][j] = (short)f2bf(W2[k * 256 + colc]);
                }
            }
        }
    }
    // ---- stage W3 fragments into LDS (zero-padded to 16 cols) ----
    for (int e = tid; e < 4096; e += NT) {
        const int j = e & 7, ln = (e >> 3) & 63, ks = e >> 9;
        const int k = ks * 32 + (ln >> 4) * 8 + j;
        const int n = ln & 15;
        w3l[e] = (n < 5) ? f2bf(W3[k * 5 + n]) : (unsigned short)0;
    }
    w0l[tid] = W0[tid];                      // rows 0,1 (NT == 512 exactly)
    // ---- bulk-stage ALL path_seed rows for this block (coalesced, one-time) ----
    for (int e = tid; e < LT * 16; e += NT) {
        sseed[e] = path_seed[(size_t)(e >> 4) * (PP * 2) + (size_t)pbase * 2 + (e & 15)];
    }

    // step-invariant hoists (paired-col bias indices)
    const float bv1a = b1[wv * 32 + 2 * col];
    const float bv1b = b1[wv * 32 + 2 * col + 1];
    const float bv2a = b2[wv * 32 + 2 * col];
    const float bv2b = b2[wv * 32 + 2 * col + 1];
    float4v b3v;                          // tail bias, D^T row n = quad*4+r
#pragma unroll
    for (int r = 0; r < 4; ++r) {
        const int n = quad * 4 + r;
        b3v[r] = (n < 5) ? b3[n] : 0.0f;
    }

    if (tid < PB) {
        const int p = tid, gp = pbase + p;
        pbuf[p * 202 + 0] = obs_init[gp * 2 + 0];
        pbuf[p * 202 + 101] = obs_init[gp * 2 + 1];
    }

    // ---- t=0 layer 0: wave wv = path lp, 4 cols/lane starting at lane*4 ----
    const int c0l0 = lane * 4;
    {
        const int gp = pbase + lp;
        float xk[8];
        xk[0] = obs_init[gp * 2 + 0];
        xk[1] = obs_init[gp * 2 + 1];
#pragma unroll
        for (int f = 0; f < 6; ++f) xk[2 + f] = feature_init[gp * 6 + f];
        float a0, a1, a2, a3;
        {
            const float4 bq = ldg4(b0 + c0l0);
            a0 = bq.x; a1 = bq.y; a2 = bq.z; a3 = bq.w;
        }
#pragma unroll
        for (int k = 0; k < 8; ++k) {
            const float4 w = ldg4(W0 + k * HH + c0l0);
            a0 = fmaf(xk[k], w.x, a0); a1 = fmaf(xk[k], w.y, a1);
            a2 = fmaf(xk[k], w.z, a2); a3 = fmaf(xk[k], w.w, a3);
        }
        uint2 ov;
        ov.x = cvtpk(fmaxf(a0, 0.0f), fmaxf(a1, 0.0f));
        ov.y = cvtpk(fmaxf(a2, 0.0f), fmaxf(a3, 0.0f));
        *(uint2*)&hA[lp * SH + c0l0] = ov;
    }
    // preload cfeat for t=1 (4 cols per lane)
    float4 cf = ldg4(cfeat + 256 + c0l0);

    for (int t = 0; t < LT; ++t) {
        // ---- layer 0 (t>=1): wave = path lp, 4 cols/lane; st broadcast read ----
        if (t > 0) {
            const float s0 = st[lp][0];
            const float s1 = st[lp][1];
            const float4 wa = *(const float4*)&w0l[c0l0];
            const float4 wb = *(const float4*)&w0l[256 + c0l0];
            uint2 ov;
            ov.x = cvtpk(fmaxf(fmaf(s0, wa.x, fmaf(s1, wb.x, cf.x)), 0.0f),
                         fmaxf(fmaf(s0, wa.y, fmaf(s1, wb.y, cf.y)), 0.0f));
            ov.y = cvtpk(fmaxf(fmaf(s0, wa.z, fmaf(s1, wb.z, cf.z)), 0.0f),
                         fmaxf(fmaf(s0, wa.w, fmaf(s1, wb.w, cf.w)), 0.0f));
            *(uint2*)&hA[lp * SH + c0l0] = ov;
        }
        __syncthreads();                       // B: h0 (hA) ready

        // prefetch next step's cfeat HERE: drains at barC ~800cyc later -> hidden
        {
            const int ti = (t + 1 < LT) ? (t + 1) : (LT - 1);
            cf = ldg4(cfeat + ti * 256 + c0l0);
        }

        mfma256_reg2(wf1, bv1a, bv1b, hA, hB, wv, lane);   // h1 = relu(h0 @ W1 + b1)
        __syncthreads();                       // C: h1 (hB) ready
        mfma256_reg2(wf2, bv2a, bv2b, hB, hC, wv, lane);   // h2 = relu(h1 @ W2 + b2)
        __syncthreads();                       // D: h2 (hC) ready

        // ---- layer 3 + sampling: WAVE 0 ONLY. Operand-SWAPPED MFMA with W3
        //      frags from LDS; __shfl epilogue. Valid paths: lanes<8. ----
        if (wv == 0) {
            float4v accA = b3v;
            float4v accB = {0.0f, 0.0f, 0.0f, 0.0f};
            const unsigned short* arow = hC + (col & 7) * SH + quad * 8;
#pragma unroll
            for (int ks = 0; ks < 4; ++ks) {    // two chains of 4 (halve dep latency)
                short8 a0 = *(const short8*)(arow + ks * 32);
                short8 a1 = *(const short8*)(arow + (ks + 4) * 32);
                short8 b0f = *(const short8*)(w3l + (ks * 64 + lane) * 8);
                short8 b1f = *(const short8*)(w3l + ((ks + 4) * 64 + lane) * 8);
                accA = __builtin_amdgcn_mfma_f32_16x16x32_bf16(b0f, a0, accA, 0, 0, 0);
                accB = __builtin_amdgcn_mfma_f32_16x16x32_bf16(b1f, a1, accB, 0, 0, 0);
            }
            // D^T: col = path p, row quad*4+r = output n. Lane(quad0,p<8): n=0..3;
            // lane(quad1,p): n=4 in reg 0. One shuffle brings s22 to quad0.
            const float4v s4 = accA + accB;
            const float s22r = __shfl(s4[0], (lane + 16) & 63);
            if (lane < PB) {
                const int p = lane;            // col == lane, quad == 0 here
                const float e0 = sseed[t * 16 + 2 * p];       // LDS, no vmcnt drain
                const float e1 = sseed[t * 16 + 2 * p + 1];
                const float mu0 = s4[0];
                const float mu1 = s4[1];
                const float s11 = softplus_fast(s4[2]);
                const float s21 = s4[3];
                const float s22 = softplus_fast(s22r);
                const float ps0 = (t == 0) ? pbuf[p * 202 + 0] : st[p][0];
                const float ps1 = (t == 0) ? pbuf[p * 202 + 101] : st[p][1];
                const float n0 = softplus_fast(ps0 + DTf * mu0 + SQ * (s11 * e0));
                const float n1 = softplus_fast(ps1 + DTf * mu1 + SQ * (s21 * e0 + s22 * e1));
                st[p][0] = n0;
                st[p][1] = n1;
                pbuf[p * 202 + (t + 1)] = n0;
                pbuf[p * 202 + 101 + (t + 1)] = n1;
                mbuf[p * 200 + t * 2 + 0] = mu0;
                mbuf[p * 200 + t * 2 + 1] = mu1;
                sbuf[p * 400 + t * 4 + 0] = s11;
                sbuf[p * 400 + t * 4 + 1] = 0.0f;
                sbuf[p * 400 + t * 4 + 2] = s21;
                sbuf[p * 400 + t * 4 + 3] = s22;
            }
        }
        __syncthreads();                       // E: st ready for next layer0
    }

    // ---- coalesced output write phase ----
    float* __restrict__ pdst = out + (size_t)pbase * 202;
    float* __restrict__ mdst = out + (size_t)PP * 202 + (size_t)pbase * 200;
    float* __restrict__ sdst = out + (size_t)PP * 202 + (size_t)PP * 200 + (size_t)pbase * 400;
    for (int i = tid; i < PB * 202 / 4; i += NT) ((float4*)pdst)[i] = ((const float4*)pbuf)[i];
    for (int i = tid; i < PB * 200 / 4; i += NT) ((float4*)mdst)[i] = ((const float4*)mbuf)[i];
    for (int i = tid; i < PB * 400 / 4; i += NT) ((float4*)sdst)[i] = ((const float4*)sbuf)[i];
}

extern "C" void kernel_launch(void* const* d_in, const int* in_sizes, int n_in,
                              void* d_out, int out_size, void* d_ws, size_t ws_size,
                              hipStream_t stream) {
    (void)in_sizes; (void)n_in; (void)out_size; (void)ws_size;
    float* cfeat = (float*)d_ws;             // 100*256 fp32 = 100 KB
    prep_cfeat<<<LT - 1, 256, 0, stream>>>(
        (const float*)d_in[0],   // W0
        (const float*)d_in[1],   // b0
        (const float*)d_in[9],   // feature_init (t0)
        (const float*)d_in[10],  // tn_store
        (const float*)d_in[11],  // x1_store
        (const float*)d_in[12],  // x2_store
        cfeat);
    lv_kernel<<<PP / PB, NT, 0, stream>>>(
        (const float*)d_in[0],   // W0
        (const float*)d_in[1],   // b0
        (const float*)d_in[2],   // W1
        (const float*)d_in[3],   // b1
        (const float*)d_in[4],   // W2
        (const float*)d_in[5],   // b2
        (const float*)d_in[6],   // W3
        (const float*)d_in[7],   // b3
        (const float*)d_in[8],   // obs_init
        (const float*)d_in[9],   // feature_init
        (const float*)d_in[13],  // path_seed
        cfeat,
        (float*)d_out);
}

// Round 15
// 268.446 us; speedup vs baseline: 4.5247x; 4.5247x over previous
//
#include <hip/hip_runtime.h>
#include <math.h>

// LotkaVolterra neural-SDE rollout. P=4096, H=256, 100 sequential steps.
// R30 = R24/R28 REVERT (session optimum: ~203us steady, ~267us wall; from
// 322.9us at session start). R29 (PB=8, 2 blocks/CU) catastrophically spilled:
// __launch_bounds__(512,4) halves the UNIFIED VGPR+AGPR budget to 128, but the
// kernel needs ~192+ unified (reported VGPR_Count=128 counts arch VGPRs only;
// the 128 weight-fragment regs live in AGPRs). Result: VGPR=64, FETCH 3.5GB,
// 1153us. CONFIRMED: the weight-fragment-resident design requires 2 waves/SIMD;
// both occupancy doors (R17: 4 col-groups/wave; R29: 2 blocks/CU) are closed
// by the same register wall.
// Design-space summary (all harness-measured):
//  - occupancy: closed (R17/R29 spills)     - LDS banking: width-intrinsic
//  - latency/barrier: harvested (R21/23/24) - tail parallel: loses (R27)
//  - spill-free hoists: exhausted (R19/R20) - swizzles: net-negative (R25/26)
// Structure: 8 waves (NT=512, 2/SIMD), 2 adjacent col-groups/wave, paired-col
// cvt_pk b32 epilogue, wave-0 swapped-MFMA tail + __shfl, seeds LDS-staged,
// cfeat prefetch after barB (vmcnt drain hidden at barC).

#define PP 4096
#define HH 256
#define LT 100
#define PB 16
#define SH 264          // bf16 LDS row stride: 528 B = 33*16B (MUST stay 16B-multiple)
#define NT 512

typedef __attribute__((ext_vector_type(8))) short short8;
typedef __attribute__((ext_vector_type(4))) short short4v;
typedef __attribute__((ext_vector_type(4))) float float4v;

__device__ __forceinline__ float softplus_fast(float x) {
    const float e = __expf(-fabsf(x));
    return fmaxf(x, 0.0f) + __logf(1.0f + e);
}
__device__ __forceinline__ unsigned short f2bf(float f) {   // RNE fp32->bf16
    unsigned int u = __float_as_uint(f);
    u += 0x7fffu + ((u >> 16) & 1u);
    return (unsigned short)(u >> 16);
}
// one-instruction packed RNE conversion: D = {lo16: bf16(a), hi16: bf16(b)}
__device__ __forceinline__ unsigned int cvtpk(float a, float b) {
    unsigned int r;
    asm("v_cvt_pk_bf16_f32 %0, %1, %2" : "=v"(r) : "v"(a), "v"(b));
    return r;
}
__device__ __forceinline__ float4 ldg4(const float* p) { return *(const float4*)p; }

// ---- parallel prologue: block b handles t = b+1 (R14-verified correct) ----
__global__ void prep_cfeat(const float* __restrict__ W0, const float* __restrict__ b0,
                           const float* __restrict__ feature_init,
                           const float* __restrict__ tn_store,
                           const float* __restrict__ x1_store,
                           const float* __restrict__ x2_store,
                           float* __restrict__ cfeat) {
    const int t = blockIdx.x + 1;             // 1..99
    const int col = threadIdx.x;
    // exact sequential fp32 tval chain (matches ref's scan accumulation)
    float tval = feature_init[0];
    for (int i = 0; i < t; ++i) tval += 0.1f;
    const float tn = tn_store[t - 1], x1 = x1_store[t - 1], x2 = x2_store[t - 1];
    const float w2c = W0[2 * 256 + col], w3c = W0[3 * 256 + col];
    const float w46 = W0[4 * 256 + col] + W0[6 * 256 + col];
    const float w57 = W0[5 * 256 + col] + W0[7 * 256 + col];
    cfeat[t * 256 + col] = b0[col] + tval * w2c + tn * w3c + x1 * w46 + x2 * w57;
}

// 256->256 bf16 MFMA layer, TWO ADJACENT col-groups/wave (paired-col mapping):
// acc0 = even cols wv*32+2c, acc1 = odd cols wv*32+2c+1 -> one cvt_pk + one
// b32 store per r (epilogue = 4 fmax-pairs + 4 cvt_pk + 4 ds_write_b32).
__device__ __forceinline__ void mfma256_reg2(const short8 (&wf)[2][8], float bv0, float bv1,
                                             const unsigned short* __restrict__ hin,
                                             unsigned short* __restrict__ hout,
                                             int wv, int lane) {
    const int quad = lane >> 4, col = lane & 15;
    float4v acc0 = {bv0, bv0, bv0, bv0};
    float4v acc1 = {bv1, bv1, bv1, bv1};
    const unsigned short* arow = hin + col * SH + quad * 8;
#pragma unroll
    for (int ks = 0; ks < 8; ++ks) {
        short8 a = *(const short8*)(arow + ks * 32);
        acc0 = __builtin_amdgcn_mfma_f32_16x16x32_bf16(a, wf[0][ks], acc0, 0, 0, 0);
        acc1 = __builtin_amdgcn_mfma_f32_16x16x32_bf16(a, wf[1][ks], acc1, 0, 0, 0);
    }
    // C/D layout: col = lane&15, row p = quad*4 + reg (m89-verified).
#pragma unroll
    for (int r = 0; r < 4; ++r) {
        const unsigned int pk = cvtpk(fmaxf(acc0[r], 0.0f), fmaxf(acc1[r], 0.0f));
        *(unsigned int*)&hout[(quad * 4 + r) * SH + wv * 32 + 2 * col] = pk;
    }
}

__global__ __launch_bounds__(NT, 2)
void lv_kernel(const float* __restrict__ W0, const float* __restrict__ b0,
               const float* __restrict__ W1, const float* __restrict__ b1,
               const float* __restrict__ W2, const float* __restrict__ b2,
               const float* __restrict__ W3, const float* __restrict__ b3,
               const float* __restrict__ obs_init, const float* __restrict__ feature_init,
               const float* __restrict__ path_seed,
               const float* __restrict__ cfeat,
               float* __restrict__ out) {
    __shared__ unsigned short hA[PB * SH];
    __shared__ unsigned short hB[PB * SH];
    __shared__ unsigned short hC[PB * SH];
    __shared__ __align__(16) unsigned short w3l[4096];   // W3 fragments (zero-padded)
    __shared__ __align__(16) float w0l[512];             // W0 rows 0,1
    __shared__ __align__(16) float sseed[LT * 32];       // ALL seeds for this block (12.8KB)
    __shared__ float st[PB][2];                          // path state
    __shared__ __align__(16) float pbuf[PB * 202];
    __shared__ __align__(16) float mbuf[PB * 200];
    __shared__ __align__(16) float sbuf[PB * 400];

    const int tid = threadIdx.x;
    const int lane = tid & 63;
    const int wv = tid >> 6;            // wave 0..7; owns col pairs wv*32+2c,+1
    const int quad = lane >> 4;
    const int col = lane & 15;
    const int hl = lane & 31;           // half-lane id (layer-0 col index base)
    const int lp = 2 * wv + (lane >> 5);// layer-0 path handled by this lane
    const int pbase = blockIdx.x * PB;

    const float DTf = 0.1f;
    const float SQ = 0.31622776601683794f;  // sqrt(0.1)

    // ---- per-wave W1/W2 B-fragments (2 ADJACENT col-groups) from global ----
    short8 wf1[2][8], wf2[2][8];
    {
#pragma unroll
        for (int g = 0; g < 2; ++g) {
            const int colc = wv * 32 + 2 * col + g;
#pragma unroll
            for (int ks = 0; ks < 8; ++ks) {
#pragma unroll
                for (int j = 0; j < 8; ++j) {
                    const int k = ks * 32 + quad * 8 + j;
                    wf1[g][ks][j] = (short)f2bf(W1[k * 256 + colc]);
                    wf2[g][ks][j] = (short)f2bf(W2[k * 256 + colc]);
                }
            }
        }
    }
    // ---- stage W3 fragments into LDS (zero-padded to 16 cols) ----
    for (int e = tid; e < 4096; e += NT) {
        const int j = e & 7, ln = (e >> 3) & 63, ks = e >> 9;
        const int k = ks * 32 + (ln >> 4) * 8 + j;
        const int n = ln & 15;
        w3l[e] = (n < 5) ? f2bf(W3[k * 5 + n]) : (unsigned short)0;
    }
    w0l[tid] = W0[tid];                      // rows 0,1 (NT == 512 exactly)
    // ---- bulk-stage ALL path_seed rows for this block (coalesced, one-time) ----
    for (int e = tid; e < LT * 32; e += NT) {
        sseed[e] = path_seed[(size_t)(e >> 5) * (PP * 2) + (size_t)pbase * 2 + (e & 31)];
    }

    // step-invariant hoists (paired-col bias indices)
    const float bv1a = b1[wv * 32 + 2 * col];
    const float bv1b = b1[wv * 32 + 2 * col + 1];
    const float bv2a = b2[wv * 32 + 2 * col];
    const float bv2b = b2[wv * 32 + 2 * col + 1];
    float4v b3v;                          // tail bias, D^T row n = quad*4+r
#pragma unroll
    for (int r = 0; r < 4; ++r) {
        const int n = quad * 4 + r;
        b3v[r] = (n < 5) ? b3[n] : 0.0f;
    }

    if (tid < PB) {
        const int p = tid, gp = pbase + p;
        pbuf[p * 202 + 0] = obs_init[gp * 2 + 0];
        pbuf[p * 202 + 101] = obs_init[gp * 2 + 1];
    }

    // ---- t=0 layer 0: lane handles path lp, 8 cols starting at hl*8 ----
    {
        const int gp = pbase + lp;
        float xk[8];
        xk[0] = obs_init[gp * 2 + 0];
        xk[1] = obs_init[gp * 2 + 1];
#pragma unroll
        for (int f = 0; f < 6; ++f) xk[2 + f] = feature_init[gp * 6 + f];
        const int c0 = hl * 8;
        float a[8];
        {
            const float4 ba = ldg4(b0 + c0);
            const float4 bb = ldg4(b0 + c0 + 4);
            a[0] = ba.x; a[1] = ba.y; a[2] = ba.z; a[3] = ba.w;
            a[4] = bb.x; a[5] = bb.y; a[6] = bb.z; a[7] = bb.w;
        }
#pragma unroll
        for (int k = 0; k < 8; ++k) {
            const float4 wa = ldg4(W0 + k * HH + c0);
            const float4 wb = ldg4(W0 + k * HH + c0 + 4);
            a[0] = fmaf(xk[k], wa.x, a[0]); a[1] = fmaf(xk[k], wa.y, a[1]);
            a[2] = fmaf(xk[k], wa.z, a[2]); a[3] = fmaf(xk[k], wa.w, a[3]);
            a[4] = fmaf(xk[k], wb.x, a[4]); a[5] = fmaf(xk[k], wb.y, a[5]);
            a[6] = fmaf(xk[k], wb.z, a[6]); a[7] = fmaf(xk[k], wb.w, a[7]);
        }
        uint4 ov;
        ov.x = cvtpk(fmaxf(a[0], 0.0f), fmaxf(a[1], 0.0f));
        ov.y = cvtpk(fmaxf(a[2], 0.0f), fmaxf(a[3], 0.0f));
        ov.z = cvtpk(fmaxf(a[4], 0.0f), fmaxf(a[5], 0.0f));
        ov.w = cvtpk(fmaxf(a[6], 0.0f), fmaxf(a[7], 0.0f));
        *(uint4*)&hA[lp * SH + c0] = ov;
    }
    // preload cfeat for t=1 (8 cols per lane; one-time drain at first barB is fine)
    float4 cf0 = ldg4(cfeat + 256 + hl * 8);
    float4 cf1 = ldg4(cfeat + 256 + hl * 8 + 4);

    for (int t = 0; t < LT; ++t) {
        // ---- layer 0 (t>=1): lane = path lp, 8 cols; st from LDS broadcast ----
        if (t > 0) {
            const float s0 = st[lp][0];
            const float s1 = st[lp][1];
            const int c0 = hl * 8;
            const float4 wa0 = *(const float4*)&w0l[c0];
            const float4 wa1 = *(const float4*)&w0l[c0 + 4];
            const float4 wb0 = *(const float4*)&w0l[256 + c0];
            const float4 wb1 = *(const float4*)&w0l[256 + c0 + 4];
            uint4 ov;
            ov.x = cvtpk(fmaxf(fmaf(s0, wa0.x, fmaf(s1, wb0.x, cf0.x)), 0.0f),
                         fmaxf(fmaf(s0, wa0.y, fmaf(s1, wb0.y, cf0.y)), 0.0f));
            ov.y = cvtpk(fmaxf(fmaf(s0, wa0.z, fmaf(s1, wb0.z, cf0.z)), 0.0f),
                         fmaxf(fmaf(s0, wa0.w, fmaf(s1, wb0.w, cf0.w)), 0.0f));
            ov.z = cvtpk(fmaxf(fmaf(s0, wa1.x, fmaf(s1, wb1.x, cf1.x)), 0.0f),
                         fmaxf(fmaf(s0, wa1.y, fmaf(s1, wb1.y, cf1.y)), 0.0f));
            ov.w = cvtpk(fmaxf(fmaf(s0, wa1.z, fmaf(s1, wb1.z, cf1.z)), 0.0f),
                         fmaxf(fmaf(s0, wa1.w, fmaf(s1, wb1.w, cf1.w)), 0.0f));
            *(uint4*)&hA[lp * SH + c0] = ov;
        }
        __syncthreads();                       // B: h0 (hA) ready

        // prefetch next step's cfeat HERE: drains at barC ~800cyc later -> hidden
        {
            const int ti = (t + 1 < LT) ? (t + 1) : (LT - 1);
            cf0 = ldg4(cfeat + ti * 256 + hl * 8);
            cf1 = ldg4(cfeat + ti * 256 + hl * 8 + 4);
        }

        mfma256_reg2(wf1, bv1a, bv1b, hA, hB, wv, lane);   // h1 = relu(h0 @ W1 + b1)
        __syncthreads();                       // C: h1 (hB) ready
        mfma256_reg2(wf2, bv2a, bv2b, hB, hC, wv, lane);   // h2 = relu(h1 @ W2 + b2)
        __syncthreads();                       // D: h2 (hC) ready

        // ---- layer 3 + sampling: WAVE 0 ONLY. Operand-SWAPPED MFMA with W3
        //      frags from LDS (R18-verified); __shfl epilogue (R19-verified). ----
        if (wv == 0) {
            float4v accA = b3v;
            float4v accB = {0.0f, 0.0f, 0.0f, 0.0f};
            const unsigned short* arow = hC + col * SH + quad * 8;
#pragma unroll
            for (int ks = 0; ks < 4; ++ks) {    // two chains of 4 (halve dep latency)
                short8 a0 = *(const short8*)(arow + ks * 32);
                short8 a1 = *(const short8*)(arow + (ks + 4) * 32);
                short8 b0f = *(const short8*)(w3l + (ks * 64 + lane) * 8);
                short8 b1f = *(const short8*)(w3l + ((ks + 4) * 64 + lane) * 8);
                accA = __builtin_amdgcn_mfma_f32_16x16x32_bf16(b0f, a0, accA, 0, 0, 0);
                accB = __builtin_amdgcn_mfma_f32_16x16x32_bf16(b1f, a1, accB, 0, 0, 0);
            }
            // D^T: col = path p, row quad*4+r = output n. Lane(quad0,p): n=0..3;
            // lane(quad1,p): n=4 in reg 0. One shuffle brings s22 to quad0.
            const float4v s4 = accA + accB;
            const float s22r = __shfl(s4[0], (lane + 16) & 63);
            if (lane < 16) {
                const int p = lane;            // col == lane, quad == 0 here
                const float e0 = sseed[t * 32 + 2 * p];       // LDS, no vmcnt drain
                const float e1 = sseed[t * 32 + 2 * p + 1];
                const float mu0 = s4[0];
                const float mu1 = s4[1];
                const float s11 = softplus_fast(s4[2]);
                const float s21 = s4[3];
                const float s22 = softplus_fast(s22r);
                const float ps0 = (t == 0) ? pbuf[p * 202 + 0] : st[p][0];
                const float ps1 = (t == 0) ? pbuf[p * 202 + 101] : st[p][1];
                const float n0 = softplus_fast(ps0 + DTf * mu0 + SQ * (s11 * e0));
                const float n1 = softplus_fast(ps1 + DTf * mu1 + SQ * (s21 * e0 + s22 * e1));
                st[p][0] = n0;
                st[p][1] = n1;
                pbuf[p * 202 + (t + 1)] = n0;
                pbuf[p * 202 + 101 + (t + 1)] = n1;
                mbuf[p * 200 + t * 2 + 0] = mu0;
                mbuf[p * 200 + t * 2 + 1] = mu1;
                sbuf[p * 400 + t * 4 + 0] = s11;
                sbuf[p * 400 + t * 4 + 1] = 0.0f;
                sbuf[p * 400 + t * 4 + 2] = s21;
                sbuf[p * 400 + t * 4 + 3] = s22;
            }
        }
        __syncthreads();                       // E: st ready for next layer0
    }

    // ---- coalesced output write phase ----
    float* __restrict__ pdst = out + (size_t)pbase * 202;
    float* __restrict__ mdst = out + (size_t)PP * 202 + (size_t)pbase * 200;
    float* __restrict__ sdst = out + (size_t)PP * 202 + (size_t)PP * 200 + (size_t)pbase * 400;
    for (int i = tid; i < PB * 202 / 4; i += NT) ((float4*)pdst)[i] = ((const float4*)pbuf)[i];
    for (int i = tid; i < PB * 200 / 4; i += NT) ((float4*)mdst)[i] = ((const float4*)mbuf)[i];
    for (int i = tid; i < PB * 400 / 4; i += NT) ((float4*)sdst)[i] = ((const float4*)sbuf)[i];
}

extern "C" void kernel_launch(void* const* d_in, const int* in_sizes, int n_in,
                              void* d_out, int out_size, void* d_ws, size_t ws_size,
                              hipStream_t stream) {
    (void)in_sizes; (void)n_in; (void)out_size; (void)ws_size;
    float* cfeat = (float*)d_ws;             // 100*256 fp32 = 100 KB
    prep_cfeat<<<LT - 1, 256, 0, stream>>>(
        (const float*)d_in[0],   // W0
        (const float*)d_in[1],   // b0
        (const float*)d_in[9],   // feature_init (t0)
        (const float*)d_in[10],  // tn_store
        (const float*)d_in[11],  // x1_store
        (const float*)d_in[12],  // x2_store
        cfeat);
    lv_kernel<<<PP / PB, NT, 0, stream>>>(
        (const float*)d_in[0],   // W0
        (const float*)d_in[1],   // b0
        (const float*)d_in[2],   // W1
        (const float*)d_in[3],   // b1
        (const float*)d_in[4],   // W2
        (const float*)d_in[5],   // b2
        (const float*)d_in[6],   // W3
        (const float*)d_in[7],   // b3
        (const float*)d_in[8],   // obs_init
        (const float*)d_in[9],   // feature_init
        (const float*)d_in[13],  // path_seed
        cfeat,
        (float*)d_out);
}